// Round 1
// 502.664 us; speedup vs baseline: 1.2510x; 1.2510x over previous
//
#include <hip/hip_runtime.h>

typedef _Float16 f16x8 __attribute__((ext_vector_type(8)));
typedef _Float16 f16x4 __attribute__((ext_vector_type(4)));
typedef float    f32x4 __attribute__((ext_vector_type(4)));

#define SPLIT_SCALE 4096.0f
#define SPLIT_INV   (1.0f / 4096.0f)

// async global->LDS DMA, 16 bytes/lane (LDS dest = wave-uniform base + lane*16)
__device__ __forceinline__ void gld_lds16(const void* g, void* l) {
    __builtin_amdgcn_global_load_lds(
        (const __attribute__((address_space(1))) unsigned int*)g,
        (__attribute__((address_space(3))) unsigned int*)l,
        16, 0, 0);
}

// fp32 x8 -> f16 hi + f16 lo*4096
__device__ __forceinline__ void cvt8(const float4 a, const float4 b,
                                     f16x8& h, f16x8& l) {
    float v[8] = {a.x, a.y, a.z, a.w, b.x, b.y, b.z, b.w};
#pragma unroll
    for (int j = 0; j < 8; ++j) {
        _Float16 x = (_Float16)v[j];
        h[j] = x;
        l[j] = (_Float16)((v[j] - (float)x) * SPLIT_SCALE);
    }
}

// weights fp32 -> (hi, lo) f16
__global__ __launch_bounds__(256) void k_cvt(
    const float* __restrict__ src, _Float16* __restrict__ h, _Float16* __restrict__ l)
{
    const size_t i = ((size_t)blockIdx.x * 256 + threadIdx.x) * 8;
    float4 v0 = *(const float4*)(src + i);
    float4 v1 = *(const float4*)(src + i + 4);
    f16x8 hh, ll;
    cvt8(v0, v1, hh, ll);
    *(f16x8*)(h + i) = hh;
    *(f16x8*)(l + i) = ll;
}

// ---------------------------------------------------------------------------
// Front GEMM core: C[128x128] = A_f32[M,K] @ (Bh+Bl/4096)[N,K]^T, BK=64.
// Wave w computes rows w*32..w*32+31 x all 128 cols (distinct A rows/wave).
// A: direct global->register fragments (row l15, cols quad*8..+7), inline
//    hi/lo split; WAR on frag regs orders convert after MFMA consumption.
// B: LDS DMA double-buffer, XOR-swizzled 16B chunks (conflict-free ds_read).
// nIt: number of BK=64 steps (callers pre-offset A/Bh/Bl by the K start).
// ---------------------------------------------------------------------------
__device__ __forceinline__ void front_core(
    const float* __restrict__ A,
    const _Float16* __restrict__ Bh_g, const _Float16* __restrict__ Bl_g,
    float* __restrict__ C, int K, int m0, int n0, int nIt)
{
    __shared__ _Float16 BhL[2][128 * 64];
    __shared__ _Float16 BlL[2][128 * 64];

    const int tid  = threadIdx.x;
    const int lane = tid & 63;
    const int wave = tid >> 6;
    const int quad = lane >> 4;
    const int l15  = lane & 15;

    // --- B DMA: wave stages rows wave*32+8j+(lane>>3), swizzled 16B chunk ---
    const int srow   = wave * 32 + (lane >> 3);
    const int schunk = (((lane & 7) ^ ((lane >> 3) & 7))) * 8;   // f16 elems
    const size_t gB  = (size_t)(n0 + srow) * (size_t)K + schunk;
    const int ldsw   = (wave * 32) * 64;                          // elem offset

    // --- A direct fragment pointers: rows wave*32 + {0,16} + l15 ---
    const float* A0 = A + (size_t)(m0 + wave * 32 + l15) * (size_t)K + quad * 8;
    const float* A1 = A0 + (size_t)16 * K;

    f32x4 accm[2][8], accc[2][8];
#pragma unroll
    for (int i = 0; i < 2; ++i)
#pragma unroll
        for (int j = 0; j < 8; ++j) {
            accm[i][j] = (f32x4){0.f, 0.f, 0.f, 0.f};
            accc[i][j] = (f32x4){0.f, 0.f, 0.f, 0.f};
        }

    float4 ar[8];               // pending A fp32: [i*4 + kc*2 + half]
    f16x8 fah[2][2], fal[2][2]; // current A frags [i][kc]

    // ---- prologue: B tile0 DMA + A tile0 load/convert ----
#pragma unroll
    for (int j = 0; j < 4; ++j) {
        gld_lds16(Bh_g + gB + (size_t)(8 * j) * K, BhL[0] + ldsw + 8 * j * 64);
        gld_lds16(Bl_g + gB + (size_t)(8 * j) * K, BlL[0] + ldsw + 8 * j * 64);
    }
    ar[0] = *(const float4*)(A0);      ar[1] = *(const float4*)(A0 + 4);
    ar[2] = *(const float4*)(A0 + 32); ar[3] = *(const float4*)(A0 + 36);
    ar[4] = *(const float4*)(A1);      ar[5] = *(const float4*)(A1 + 4);
    ar[6] = *(const float4*)(A1 + 32); ar[7] = *(const float4*)(A1 + 36);
#pragma unroll
    for (int i = 0; i < 2; ++i)
#pragma unroll
        for (int kc = 0; kc < 2; ++kc)
            cvt8(ar[i * 4 + kc * 2], ar[i * 4 + kc * 2 + 1], fah[i][kc], fal[i][kc]);

    for (int it = 0; it < nIt; ++it) {
        __syncthreads();                 // B buf[it&1] landed
        const int cur = it & 1;
        const int nxt = cur ^ 1;
        const bool more = (it + 1) < nIt;

        if (more) {                      // prefetch tile it+1
            const size_t kb = (size_t)(it + 1) * 64;
#pragma unroll
            for (int j = 0; j < 4; ++j) {
                gld_lds16(Bh_g + gB + (size_t)(8 * j) * K + kb, BhL[nxt] + ldsw + 8 * j * 64);
                gld_lds16(Bl_g + gB + (size_t)(8 * j) * K + kb, BlL[nxt] + ldsw + 8 * j * 64);
            }
            const float* p0 = A0 + kb;
            const float* p1 = A1 + kb;
            ar[0] = *(const float4*)(p0);      ar[1] = *(const float4*)(p0 + 4);
            ar[2] = *(const float4*)(p0 + 32); ar[3] = *(const float4*)(p0 + 36);
            ar[4] = *(const float4*)(p1);      ar[5] = *(const float4*)(p1 + 4);
            ar[6] = *(const float4*)(p1 + 32); ar[7] = *(const float4*)(p1 + 36);
        }

        // ---- consume current B buffer with current A frags ----
#pragma unroll
        for (int kc = 0; kc < 2; ++kc) {
#pragma unroll
            for (int jh = 0; jh < 2; ++jh) {
                f16x8 fbh[4], fbl[4];
#pragma unroll
                for (int j = 0; j < 4; ++j) {
                    const int jj = jh * 4 + j;
                    const int p  = (((kc * 4 + quad) ^ (l15 & 7))) * 8;
                    const int e  = (jj * 16 + l15) * 64 + p;
                    fbh[j] = *(const f16x8*)&BhL[cur][e];
                    fbl[j] = *(const f16x8*)&BlL[cur][e];
                }
#pragma unroll
                for (int i = 0; i < 2; ++i)
#pragma unroll
                    for (int j = 0; j < 4; ++j) {
                        const int jj = jh * 4 + j;
                        accm[i][jj] = __builtin_amdgcn_mfma_f32_16x16x32_f16(fah[i][kc], fbh[j], accm[i][jj], 0, 0, 0);
                        accc[i][jj] = __builtin_amdgcn_mfma_f32_16x16x32_f16(fah[i][kc], fbl[j], accc[i][jj], 0, 0, 0);
                        accc[i][jj] = __builtin_amdgcn_mfma_f32_16x16x32_f16(fal[i][kc], fbh[j], accc[i][jj], 0, 0, 0);
                    }
            }
        }

        if (more) {   // convert prefetched A (WAR on fah/fal keeps this below MFMAs)
#pragma unroll
            for (int i = 0; i < 2; ++i)
#pragma unroll
                for (int kc = 0; kc < 2; ++kc)
                    cvt8(ar[i * 4 + kc * 2], ar[i * 4 + kc * 2 + 1], fah[i][kc], fal[i][kc]);
        }
    }

    // ---- epilogue: D rows quad*4+r, cols l15 ----
#pragma unroll
    for (int i = 0; i < 2; ++i)
#pragma unroll
        for (int jj = 0; jj < 8; ++jj)
#pragma unroll
            for (int r = 0; r < 4; ++r) {
                const int row = m0 + wave * 32 + i * 16 + quad * 4 + r;
                const int col = n0 + jj * 16 + l15;
                C[(size_t)row * 512 + col] = accm[i][jj][r] + accc[i][jj][r] * SPLIT_INV;
            }
}

// Grid = 512 blocks = exactly 2/CU * 256 CU -> one scheduling round (the old
// 528-block grid ran 512 blocks then a 16-block basal tail that DOUBLED the
// kernel duration; counters: occupancy 13.6 ~= 25%/2, MfmaUtil 18.4 ~= 37%/2).
// Job 0 (all blocks): one apical 128x128 tile, full K — identical chains to
// the previous kernel. Job 1 (first block of each CU, bid<256): one K-chunk
// (3-4 of 49 BK-steps) of a basal 128x128 tile into partial buffer PCb[p];
// basal is only ~3% of total FLOPs so the chunk tail is ~20 us, not 182 us.
__global__ __launch_bounds__(256, 2) void k_front(
    const float* __restrict__ TE, const float* __restrict__ SE,
    const _Float16* __restrict__ Wah, const _Float16* __restrict__ Wal,
    const _Float16* __restrict__ Wbh, const _Float16* __restrict__ Wbl,
    float* __restrict__ Abuf, float* __restrict__ PCb)
{
    const int bid = blockIdx.x;
    // apical: m-major mapping (bid, bid+128, ... share A rows on one XCD L2)
    front_core(TE, Wah, Wal, Abuf, 3136, (bid & 127) * 128, (bid >> 7) * 128, 49);

    if (bid < 256) {
        __syncthreads();   // all waves done reading LDS before re-staging
        const int p   = bid >> 4;              // K-chunk index 0..15
        const int it0 = 3 * p;                 // BK-step offset
        const int nIt = (p == 15) ? 4 : 3;     // 15*3 + 4 = 49
        const int m0  = (bid & 3) * 128;
        const int n0  = ((bid >> 2) & 3) * 128;
        front_core(SE + it0 * 64, Wbh + it0 * 64, Wbl + it0 * 64,
                   PCb + (size_t)p * 262144, 3136, m0, n0, nIt);
    }
}

// Cb = sum_p PCb[p], ordered, accumulated in fp64 (single final rounding) so
// the basal K-split perturbs the original summation chain minimally.
__global__ __launch_bounds__(256) void k_comb(
    const float* __restrict__ PCb, float* __restrict__ Cb)
{
    const int i = (blockIdx.x * 256 + threadIdx.x) * 4;
    double s0 = 0.0, s1 = 0.0, s2 = 0.0, s3 = 0.0;
#pragma unroll
    for (int p = 0; p < 16; ++p) {
        float4 v = *(const float4*)(PCb + (size_t)p * 262144 + i);
        s0 += v.x; s1 += v.y; s2 += v.z; s3 += v.w;
    }
    *(float4*)(Cb + i) = make_float4((float)s0, (float)s1, (float)s2, (float)s3);
}

// H = SP(f16 exact) @ (W1h + W1l/4096)^T. A direct register frags (no cvt).
__global__ __launch_bounds__(256, 2) void k_gemm3(
    const _Float16* __restrict__ SPh, const _Float16* __restrict__ W1h,
    const _Float16* __restrict__ W1l, float* __restrict__ H)
{
    __shared__ _Float16 BhL[2][128 * 64];
    __shared__ _Float16 BlL[2][128 * 64];

    const int bid = blockIdx.x;
    const int m0 = (bid & 127) * 128, n0 = (bid >> 7) * 128;
    const int tid  = threadIdx.x;
    const int lane = tid & 63;
    const int wave = tid >> 6;
    const int quad = lane >> 4;
    const int l15  = lane & 15;

    const int srow   = wave * 32 + (lane >> 3);
    const int schunk = (((lane & 7) ^ ((lane >> 3) & 7))) * 8;
    const size_t gB  = (size_t)(n0 + srow) * 512 + schunk;
    const int ldsw   = (wave * 32) * 64;

    const _Float16* A0 = SPh + (size_t)(m0 + wave * 32 + l15) * 512 + quad * 8;
    const _Float16* A1 = A0 + (size_t)16 * 512;

    f32x4 accm[2][8], accl[2][8];
#pragma unroll
    for (int i = 0; i < 2; ++i)
#pragma unroll
        for (int j = 0; j < 8; ++j) {
            accm[i][j] = (f32x4){0.f, 0.f, 0.f, 0.f};
            accl[i][j] = (f32x4){0.f, 0.f, 0.f, 0.f};
        }

#pragma unroll
    for (int j = 0; j < 4; ++j) {
        gld_lds16(W1h + gB + (size_t)(8 * j) * 512, BhL[0] + ldsw + 8 * j * 64);
        gld_lds16(W1l + gB + (size_t)(8 * j) * 512, BlL[0] + ldsw + 8 * j * 64);
    }

    for (int it = 0; it < 8; ++it) {
        __syncthreads();
        const int cur = it & 1;
        const int nxt = cur ^ 1;
        if (it + 1 < 8) {
            const size_t kb = (size_t)(it + 1) * 64;
#pragma unroll
            for (int j = 0; j < 4; ++j) {
                gld_lds16(W1h + gB + (size_t)(8 * j) * 512 + kb, BhL[nxt] + ldsw + 8 * j * 64);
                gld_lds16(W1l + gB + (size_t)(8 * j) * 512 + kb, BlL[nxt] + ldsw + 8 * j * 64);
            }
        }
        // A frags: direct 16B loads in MFMA layout
        f16x8 fa[2][2];
        const size_t ka = (size_t)it * 64;
#pragma unroll
        for (int i = 0; i < 2; ++i)
#pragma unroll
            for (int kc = 0; kc < 2; ++kc)
                fa[i][kc] = *(const f16x8*)((i ? A1 : A0) + ka + kc * 32);

#pragma unroll
        for (int kc = 0; kc < 2; ++kc) {
#pragma unroll
            for (int jh = 0; jh < 2; ++jh) {
                f16x8 fbh[4], fbl[4];
#pragma unroll
                for (int j = 0; j < 4; ++j) {
                    const int jj = jh * 4 + j;
                    const int p  = (((kc * 4 + quad) ^ (l15 & 7))) * 8;
                    const int e  = (jj * 16 + l15) * 64 + p;
                    fbh[j] = *(const f16x8*)&BhL[cur][e];
                    fbl[j] = *(const f16x8*)&BlL[cur][e];
                }
#pragma unroll
                for (int i = 0; i < 2; ++i)
#pragma unroll
                    for (int j = 0; j < 4; ++j) {
                        const int jj = jh * 4 + j;
                        accm[i][jj] = __builtin_amdgcn_mfma_f32_16x16x32_f16(fa[i][kc], fbh[j], accm[i][jj], 0, 0, 0);
                        accl[i][jj] = __builtin_amdgcn_mfma_f32_16x16x32_f16(fa[i][kc], fbl[j], accl[i][jj], 0, 0, 0);
                    }
            }
        }
    }

#pragma unroll
    for (int i = 0; i < 2; ++i)
#pragma unroll
        for (int jj = 0; jj < 8; ++jj)
#pragma unroll
            for (int r = 0; r < 4; ++r) {
                const int row = m0 + wave * 32 + i * 16 + quad * 4 + r;
                const int col = n0 + jj * 16 + l15;
                H[(size_t)row * 512 + col] = accm[i][jj][r] + accl[i][jj][r] * SPLIT_INV;
            }
}

// mb/ma/ms scan over T=8; emits SP (f16, exact 0/1).
__global__ __launch_bounds__(256) void k_scan1(
    const float* __restrict__ Abuf, const float* __restrict__ Cb,
    _Float16* __restrict__ SPh)
{
    const int idx = blockIdx.x * 256 + threadIdx.x;
    const int r = idx >> 7;
    const int f = (idx & 127) << 2;
    const int b = r >> 5;

    float mb[4] = {0, 0, 0, 0}, ma[4] = {0, 0, 0, 0}, ms[4] = {0, 0, 0, 0};
#pragma unroll
    for (int t = 0; t < 8; ++t) {
        float4 av = *(const float4*)(Abuf + ((size_t)(t * 2048 + r) << 9) + f);
        float4 bv = *(const float4*)(Cb + ((size_t)(t * 64 + b) << 9) + f);
        float a[4] = {av.x, av.y, av.z, av.w};
        float ba[4] = {bv.x, bv.y, bv.z, bv.w};
        f16x4 sp;
#pragma unroll
        for (int c = 0; c < 4; ++c) {
            mb[c] = mb[c] + (ba[c] - mb[c]) * 0.5f;
            ma[c] = ma[c] + (a[c] - ma[c]) * 0.5f;
            ms[c] = ms[c] + (ma[c] + mb[c] - ms[c]) * 0.5f;
            sp[c] = (ms[c] > 1.0f) ? (_Float16)1.0f : (_Float16)0.0f;
            ms[c] = (ms[c] > 1.0f) ? 0.0f : ms[c];
        }
        *(f16x4*)(SPh + ((size_t)(t * 2048 + r) << 9) + f) = sp;
    }
}

// ml scan over T=8; emits spmean = (1/8) sum_t sp2_t.
__global__ __launch_bounds__(256) void k_scan2(
    const float* __restrict__ H, const float* __restrict__ b1,
    float* __restrict__ spmean)
{
    const int idx = blockIdx.x * 256 + threadIdx.x;
    const int r = idx >> 7;
    const int f = (idx & 127) << 2;

    float4 b1v = *(const float4*)(b1 + f);
    float bb[4] = {b1v.x, b1v.y, b1v.z, b1v.w};
    float ml[4] = {0, 0, 0, 0}, acc[4] = {0, 0, 0, 0};
#pragma unroll
    for (int t = 0; t < 8; ++t) {
        float4 hv = *(const float4*)(H + ((size_t)(t * 2048 + r) << 9) + f);
        float h[4] = {hv.x, hv.y, hv.z, hv.w};
#pragma unroll
        for (int c = 0; c < 4; ++c) {
            float hb = h[c] + bb[c];
            ml[c] = ml[c] + (hb - ml[c]) * 0.5f;
            float s2 = (ml[c] > 0.5f) ? 1.0f : 0.0f;
            acc[c] += s2;
            ml[c] = (ml[c] > 0.5f) ? 0.0f : ml[c];
        }
    }
    *(float4*)(spmean + ((size_t)r << 9) + f) =
        make_float4(acc[0] * 0.125f, acc[1] * 0.125f, acc[2] * 0.125f, acc[3] * 0.125f);
}

// out[b,l,s] = spmean[row] . W2[l] + b2[l];  out is [64,18,32]
__global__ __launch_bounds__(64) void k_out(
    const float* __restrict__ spmean, const float* __restrict__ W2,
    const float* __restrict__ b2, float* __restrict__ out)
{
    __shared__ float row[512];
    const int r = blockIdx.x;
    const int tid = threadIdx.x;

    const float4* src = (const float4*)(spmean + ((size_t)r << 9));
    ((float4*)row)[tid]      = src[tid];
    ((float4*)row)[tid + 64] = src[tid + 64];
    __syncthreads();

    if (tid < 18) {
        const float4* w = (const float4*)(W2 + (size_t)tid * 512);
        float acc = 0.0f;
#pragma unroll 4
        for (int c = 0; c < 128; ++c) {
            float4 wv = w[c];
            float4 rv = ((const float4*)row)[c];
            acc += rv.x * wv.x + rv.y * wv.y + rv.z * wv.z + rv.w * wv.w;
        }
        acc += b2[tid];
        const int b = r >> 5, s = r & 31;
        out[((size_t)(b * 18 + tid) << 5) + s] = acc;
    }
}

extern "C" void kernel_launch(void* const* d_in, const int* in_sizes, int n_in,
                              void* d_out, int out_size, void* d_ws, size_t ws_size,
                              hipStream_t stream)
{
    const float* SE = (const float*)d_in[0];   // [8,64,3136]
    const float* TE = (const float*)d_in[1];   // [8,2048,3136]
    const float* Wb = (const float*)d_in[2];   // [512,3136]
    const float* Wa = (const float*)d_in[3];   // [512,3136]
    const float* W1 = (const float*)d_in[4];   // [512,512]
    const float* b1 = (const float*)d_in[5];   // [512]
    const float* W2 = (const float*)d_in[6];   // [18,512]
    const float* b2 = (const float*)d_in[7];   // [18]
    float* out = (float*)d_out;                // [64,18,32]

    char* ws = (char*)d_ws;
    size_t off = 0;
    float*    Abuf   = (float*)(ws + off);     off += 33554432;  // [16384,512] f32 (apical, then H)
    float*    Cb     = (float*)(ws + off);     off += 1048576;   // [512,512] f32
    float*    spmean = (float*)(ws + off);     off += 4194304;   // [2048,512] f32
    _Float16* SPh    = (_Float16*)(ws + off);  off += 16777216;  // [16384,512] f16
    _Float16* W1h    = (_Float16*)(ws + off);  off += 524288;
    _Float16* W1l    = (_Float16*)(ws + off);  off += 524288;
    _Float16* Wah    = (_Float16*)(ws + off);  off += 3211264;
    _Float16* Wal    = (_Float16*)(ws + off);  off += 3211264;
    _Float16* Wbh    = (_Float16*)(ws + off);  off += 3211264;
    _Float16* Wbl    = (_Float16*)(ws + off);  off += 3211264;
    // total ~69 MB

    // Basal partial buffers alias SPh: PCb[16][512*512] f32 = 16 MB, exactly
    // SPh's size. Lifetime: written by k_front, read by k_comb, dead before
    // k_scan1 overwrites the region with SPh.
    float* PCb = (float*)SPh;

    hipLaunchKernelGGL(k_cvt, dim3(784), dim3(256), 0, stream, Wa, Wah, Wal);
    hipLaunchKernelGGL(k_cvt, dim3(784), dim3(256), 0, stream, Wb, Wbh, Wbl);
    hipLaunchKernelGGL(k_cvt, dim3(128), dim3(256), 0, stream, W1, W1h, W1l);

    hipLaunchKernelGGL(k_front, dim3(512), dim3(256), 0, stream,
                       TE, SE, Wah, Wal, Wbh, Wbl, Abuf, PCb);
    hipLaunchKernelGGL(k_comb, dim3(256), dim3(256), 0, stream, PCb, Cb);
    hipLaunchKernelGGL(k_scan1, dim3(1024), dim3(256), 0, stream, Abuf, Cb, SPh);
    hipLaunchKernelGGL(k_gemm3, dim3(512), dim3(256), 0, stream, SPh, W1h, W1l, Abuf);
    hipLaunchKernelGGL(k_scan2, dim3(1024), dim3(256), 0, stream, Abuf, b1, spmean);
    hipLaunchKernelGGL(k_out, dim3(2048), dim3(64), 0, stream, spmean, W2, b2, out);
}

// Round 2
// 485.584 us; speedup vs baseline: 1.2950x; 1.0352x over previous
//
#include <hip/hip_runtime.h>

typedef _Float16 f16x8 __attribute__((ext_vector_type(8)));
typedef _Float16 f16x4 __attribute__((ext_vector_type(4)));
typedef float    f32x4 __attribute__((ext_vector_type(4)));

#define SPLIT_SCALE 4096.0f
#define SPLIT_INV   (1.0f / 4096.0f)

// async global->LDS DMA, 16 bytes/lane (LDS dest = wave-uniform base + lane*16)
__device__ __forceinline__ void gld_lds16(const void* g, void* l) {
    __builtin_amdgcn_global_load_lds(
        (const __attribute__((address_space(1))) unsigned int*)g,
        (__attribute__((address_space(3))) unsigned int*)l,
        16, 0, 0);
}

// fp32 x8 -> f16 hi + f16 lo*4096
__device__ __forceinline__ void cvt8(const float4 a, const float4 b,
                                     f16x8& h, f16x8& l) {
    float v[8] = {a.x, a.y, a.z, a.w, b.x, b.y, b.z, b.w};
#pragma unroll
    for (int j = 0; j < 8; ++j) {
        _Float16 x = (_Float16)v[j];
        h[j] = x;
        l[j] = (_Float16)((v[j] - (float)x) * SPLIT_SCALE);
    }
}

// all three weight conversions in one launch (grid 784 + 784 + 128)
__global__ __launch_bounds__(256) void k_cvt_all(
    const float* __restrict__ Wa, const float* __restrict__ Wb,
    const float* __restrict__ W1,
    _Float16* __restrict__ Wah, _Float16* __restrict__ Wal,
    _Float16* __restrict__ Wbh, _Float16* __restrict__ Wbl,
    _Float16* __restrict__ W1h, _Float16* __restrict__ W1l)
{
    int b = blockIdx.x;
    const float* src;
    _Float16 *h, *l;
    if (b < 784)        { src = Wa; h = Wah; l = Wal; }
    else if (b < 1568)  { src = Wb; h = Wbh; l = Wbl; b -= 784; }
    else                { src = W1; h = W1h; l = W1l; b -= 1568; }

    const size_t i = ((size_t)b * 256 + threadIdx.x) * 8;
    float4 v0 = *(const float4*)(src + i);
    float4 v1 = *(const float4*)(src + i + 4);
    f16x8 hh, ll;
    cvt8(v0, v1, hh, ll);
    *(f16x8*)(h + i) = hh;
    *(f16x8*)(l + i) = ll;
}

// ---------------------------------------------------------------------------
// Front GEMM core: C[128x128] = A_f32[M,K] @ (Bh+Bl/4096)[N,K]^T, BK=64.
// Wave w computes rows w*32..w*32+31 x all 128 cols (distinct A rows/wave).
// A: direct global->register fragments (row l15, cols quad*8..+7), inline
//    hi/lo split; WAR on frag regs orders convert after MFMA consumption.
// B: LDS DMA double-buffer, XOR-swizzled 16B chunks (conflict-free ds_read).
// nIt: number of BK=64 steps (callers pre-offset A/Bh/Bl by the K start).
// ---------------------------------------------------------------------------
__device__ __forceinline__ void front_core(
    const float* __restrict__ A,
    const _Float16* __restrict__ Bh_g, const _Float16* __restrict__ Bl_g,
    float* __restrict__ C, int K, int m0, int n0, int nIt)
{
    __shared__ _Float16 BhL[2][128 * 64];
    __shared__ _Float16 BlL[2][128 * 64];

    const int tid  = threadIdx.x;
    const int lane = tid & 63;
    const int wave = tid >> 6;
    const int quad = lane >> 4;
    const int l15  = lane & 15;

    // --- B DMA: wave stages rows wave*32+8j+(lane>>3), swizzled 16B chunk ---
    const int srow   = wave * 32 + (lane >> 3);
    const int schunk = (((lane & 7) ^ ((lane >> 3) & 7))) * 8;   // f16 elems
    const size_t gB  = (size_t)(n0 + srow) * (size_t)K + schunk;
    const int ldsw   = (wave * 32) * 64;                          // elem offset

    // --- A direct fragment pointers: rows wave*32 + {0,16} + l15 ---
    const float* A0 = A + (size_t)(m0 + wave * 32 + l15) * (size_t)K + quad * 8;
    const float* A1 = A0 + (size_t)16 * K;

    f32x4 accm[2][8], accc[2][8];
#pragma unroll
    for (int i = 0; i < 2; ++i)
#pragma unroll
        for (int j = 0; j < 8; ++j) {
            accm[i][j] = (f32x4){0.f, 0.f, 0.f, 0.f};
            accc[i][j] = (f32x4){0.f, 0.f, 0.f, 0.f};
        }

    float4 ar[8];               // pending A fp32: [i*4 + kc*2 + half]
    f16x8 fah[2][2], fal[2][2]; // current A frags [i][kc]

    // ---- prologue: B tile0 DMA + A tile0 load/convert ----
#pragma unroll
    for (int j = 0; j < 4; ++j) {
        gld_lds16(Bh_g + gB + (size_t)(8 * j) * K, BhL[0] + ldsw + 8 * j * 64);
        gld_lds16(Bl_g + gB + (size_t)(8 * j) * K, BlL[0] + ldsw + 8 * j * 64);
    }
    ar[0] = *(const float4*)(A0);      ar[1] = *(const float4*)(A0 + 4);
    ar[2] = *(const float4*)(A0 + 32); ar[3] = *(const float4*)(A0 + 36);
    ar[4] = *(const float4*)(A1);      ar[5] = *(const float4*)(A1 + 4);
    ar[6] = *(const float4*)(A1 + 32); ar[7] = *(const float4*)(A1 + 36);
#pragma unroll
    for (int i = 0; i < 2; ++i)
#pragma unroll
        for (int kc = 0; kc < 2; ++kc)
            cvt8(ar[i * 4 + kc * 2], ar[i * 4 + kc * 2 + 1], fah[i][kc], fal[i][kc]);

    for (int it = 0; it < nIt; ++it) {
        __syncthreads();                 // B buf[it&1] landed
        const int cur = it & 1;
        const int nxt = cur ^ 1;
        const bool more = (it + 1) < nIt;

        if (more) {                      // prefetch tile it+1
            const size_t kb = (size_t)(it + 1) * 64;
#pragma unroll
            for (int j = 0; j < 4; ++j) {
                gld_lds16(Bh_g + gB + (size_t)(8 * j) * K + kb, BhL[nxt] + ldsw + 8 * j * 64);
                gld_lds16(Bl_g + gB + (size_t)(8 * j) * K + kb, BlL[nxt] + ldsw + 8 * j * 64);
            }
            const float* p0 = A0 + kb;
            const float* p1 = A1 + kb;
            ar[0] = *(const float4*)(p0);      ar[1] = *(const float4*)(p0 + 4);
            ar[2] = *(const float4*)(p0 + 32); ar[3] = *(const float4*)(p0 + 36);
            ar[4] = *(const float4*)(p1);      ar[5] = *(const float4*)(p1 + 4);
            ar[6] = *(const float4*)(p1 + 32); ar[7] = *(const float4*)(p1 + 36);
        }

        // ---- consume current B buffer with current A frags ----
#pragma unroll
        for (int kc = 0; kc < 2; ++kc) {
#pragma unroll
            for (int jh = 0; jh < 2; ++jh) {
                f16x8 fbh[4], fbl[4];
#pragma unroll
                for (int j = 0; j < 4; ++j) {
                    const int jj = jh * 4 + j;
                    const int p  = (((kc * 4 + quad) ^ (l15 & 7))) * 8;
                    const int e  = (jj * 16 + l15) * 64 + p;
                    fbh[j] = *(const f16x8*)&BhL[cur][e];
                    fbl[j] = *(const f16x8*)&BlL[cur][e];
                }
#pragma unroll
                for (int i = 0; i < 2; ++i)
#pragma unroll
                    for (int j = 0; j < 4; ++j) {
                        const int jj = jh * 4 + j;
                        accm[i][jj] = __builtin_amdgcn_mfma_f32_16x16x32_f16(fah[i][kc], fbh[j], accm[i][jj], 0, 0, 0);
                        accc[i][jj] = __builtin_amdgcn_mfma_f32_16x16x32_f16(fah[i][kc], fbl[j], accc[i][jj], 0, 0, 0);
                        accc[i][jj] = __builtin_amdgcn_mfma_f32_16x16x32_f16(fal[i][kc], fbh[j], accc[i][jj], 0, 0, 0);
                    }
            }
        }

        if (more) {   // convert prefetched A (WAR on fah/fal keeps this below MFMAs)
#pragma unroll
            for (int i = 0; i < 2; ++i)
#pragma unroll
                for (int kc = 0; kc < 2; ++kc)
                    cvt8(ar[i * 4 + kc * 2], ar[i * 4 + kc * 2 + 1], fah[i][kc], fal[i][kc]);
        }
    }

    // ---- epilogue: D rows quad*4+r, cols l15 ----
#pragma unroll
    for (int i = 0; i < 2; ++i)
#pragma unroll
        for (int jj = 0; jj < 8; ++jj)
#pragma unroll
            for (int r = 0; r < 4; ++r) {
                const int row = m0 + wave * 32 + i * 16 + quad * 4 + r;
                const int col = n0 + jj * 16 + l15;
                C[(size_t)row * 512 + col] = accm[i][jj][r] + accc[i][jj][r] * SPLIT_INV;
            }
}

// Grid = 512 blocks = exactly 2/CU * 256 CU -> one scheduling round.
// Job 0 (all blocks): one apical 128x128 tile, full K. Job 1 (bid<256, which
// lands one-per-CU given round-robin XCD dispatch since 256 % (8 XCD * 32 CU)
// pairs bid with bid+256 on the same CU): one K-chunk (3-4 of 49 BK-steps)
// of a basal 128x128 tile into partial buffer PCb[p].
__global__ __launch_bounds__(256, 2) void k_front(
    const float* __restrict__ TE, const float* __restrict__ SE,
    const _Float16* __restrict__ Wah, const _Float16* __restrict__ Wal,
    const _Float16* __restrict__ Wbh, const _Float16* __restrict__ Wbl,
    float* __restrict__ Abuf, float* __restrict__ PCb)
{
    const int bid = blockIdx.x;
    // apical: m-major mapping (bid, bid+128, ... share A rows on one XCD L2)
    front_core(TE, Wah, Wal, Abuf, 3136, (bid & 127) * 128, (bid >> 7) * 128, 49);

    if (bid < 256) {
        __syncthreads();   // all waves done reading LDS before re-staging
        const int p   = bid >> 4;              // K-chunk index 0..15
        const int it0 = 3 * p;                 // BK-step offset
        const int nIt = (p == 15) ? 4 : 3;     // 15*3 + 4 = 49
        const int m0  = (bid & 3) * 128;
        const int n0  = ((bid >> 2) & 3) * 128;
        front_core(SE + it0 * 64, Wbh + it0 * 64, Wbl + it0 * 64,
                   PCb + (size_t)p * 262144, 3136, m0, n0, nIt);
    }
}

// Cb = sum_p PCb[p], ordered, accumulated in fp64 (single final rounding) so
// the basal K-split perturbs the original summation chain minimally.
__global__ __launch_bounds__(256) void k_comb(
    const float* __restrict__ PCb, float* __restrict__ Cb)
{
    const int i = (blockIdx.x * 256 + threadIdx.x) * 4;
    double s0 = 0.0, s1 = 0.0, s2 = 0.0, s3 = 0.0;
#pragma unroll
    for (int p = 0; p < 16; ++p) {
        float4 v = *(const float4*)(PCb + (size_t)p * 262144 + i);
        s0 += v.x; s1 += v.y; s2 += v.z; s3 += v.w;
    }
    *(float4*)(Cb + i) = make_float4((float)s0, (float)s1, (float)s2, (float)s3);
}

// H = SP(f16 exact) @ (W1h + W1l/4096)^T. A direct register frags (no cvt).
__global__ __launch_bounds__(256, 2) void k_gemm3(
    const _Float16* __restrict__ SPh, const _Float16* __restrict__ W1h,
    const _Float16* __restrict__ W1l, float* __restrict__ H)
{
    __shared__ _Float16 BhL[2][128 * 64];
    __shared__ _Float16 BlL[2][128 * 64];

    const int bid = blockIdx.x;
    const int m0 = (bid & 127) * 128, n0 = (bid >> 7) * 128;
    const int tid  = threadIdx.x;
    const int lane = tid & 63;
    const int wave = tid >> 6;
    const int quad = lane >> 4;
    const int l15  = lane & 15;

    const int srow   = wave * 32 + (lane >> 3);
    const int schunk = (((lane & 7) ^ ((lane >> 3) & 7))) * 8;
    const size_t gB  = (size_t)(n0 + srow) * 512 + schunk;
    const int ldsw   = (wave * 32) * 64;

    const _Float16* A0 = SPh + (size_t)(m0 + wave * 32 + l15) * 512 + quad * 8;
    const _Float16* A1 = A0 + (size_t)16 * 512;

    f32x4 accm[2][8], accl[2][8];
#pragma unroll
    for (int i = 0; i < 2; ++i)
#pragma unroll
        for (int j = 0; j < 8; ++j) {
            accm[i][j] = (f32x4){0.f, 0.f, 0.f, 0.f};
            accl[i][j] = (f32x4){0.f, 0.f, 0.f, 0.f};
        }

#pragma unroll
    for (int j = 0; j < 4; ++j) {
        gld_lds16(W1h + gB + (size_t)(8 * j) * 512, BhL[0] + ldsw + 8 * j * 64);
        gld_lds16(W1l + gB + (size_t)(8 * j) * 512, BlL[0] + ldsw + 8 * j * 64);
    }

    for (int it = 0; it < 8; ++it) {
        __syncthreads();
        const int cur = it & 1;
        const int nxt = cur ^ 1;
        if (it + 1 < 8) {
            const size_t kb = (size_t)(it + 1) * 64;
#pragma unroll
            for (int j = 0; j < 4; ++j) {
                gld_lds16(W1h + gB + (size_t)(8 * j) * 512 + kb, BhL[nxt] + ldsw + 8 * j * 64);
                gld_lds16(W1l + gB + (size_t)(8 * j) * 512 + kb, BlL[nxt] + ldsw + 8 * j * 64);
            }
        }
        // A frags: direct 16B loads in MFMA layout
        f16x8 fa[2][2];
        const size_t ka = (size_t)it * 64;
#pragma unroll
        for (int i = 0; i < 2; ++i)
#pragma unroll
            for (int kc = 0; kc < 2; ++kc)
                fa[i][kc] = *(const f16x8*)((i ? A1 : A0) + ka + kc * 32);

#pragma unroll
        for (int kc = 0; kc < 2; ++kc) {
#pragma unroll
            for (int jh = 0; jh < 2; ++jh) {
                f16x8 fbh[4], fbl[4];
#pragma unroll
                for (int j = 0; j < 4; ++j) {
                    const int jj = jh * 4 + j;
                    const int p  = (((kc * 4 + quad) ^ (l15 & 7))) * 8;
                    const int e  = (jj * 16 + l15) * 64 + p;
                    fbh[j] = *(const f16x8*)&BhL[cur][e];
                    fbl[j] = *(const f16x8*)&BlL[cur][e];
                }
#pragma unroll
                for (int i = 0; i < 2; ++i)
#pragma unroll
                    for (int j = 0; j < 4; ++j) {
                        const int jj = jh * 4 + j;
                        accm[i][jj] = __builtin_amdgcn_mfma_f32_16x16x32_f16(fa[i][kc], fbh[j], accm[i][jj], 0, 0, 0);
                        accl[i][jj] = __builtin_amdgcn_mfma_f32_16x16x32_f16(fa[i][kc], fbl[j], accl[i][jj], 0, 0, 0);
                    }
            }
        }
    }

#pragma unroll
    for (int i = 0; i < 2; ++i)
#pragma unroll
        for (int jj = 0; jj < 8; ++jj)
#pragma unroll
            for (int r = 0; r < 4; ++r) {
                const int row = m0 + wave * 32 + i * 16 + quad * 4 + r;
                const int col = n0 + jj * 16 + l15;
                H[(size_t)row * 512 + col] = accm[i][jj][r] + accl[i][jj][r] * SPLIT_INV;
            }
}

// mb/ma/ms scan over T=8; emits SP (f16, exact 0/1). 8 channels/thread,
// 16B SPh stores (was 8B).
__global__ __launch_bounds__(256) void k_scan1(
    const float* __restrict__ Abuf, const float* __restrict__ Cb,
    _Float16* __restrict__ SPh)
{
    const int idx = blockIdx.x * 256 + threadIdx.x;
    const int r = idx >> 6;
    const int f = (idx & 63) << 3;
    const int b = r >> 5;

    float mb[8] = {0}, ma[8] = {0}, ms[8] = {0};
#pragma unroll
    for (int t = 0; t < 8; ++t) {
        const size_t ra = ((size_t)(t * 2048 + r) << 9) + f;
        const size_t rb = ((size_t)(t * 64 + b) << 9) + f;
        float4 av0 = *(const float4*)(Abuf + ra);
        float4 av1 = *(const float4*)(Abuf + ra + 4);
        float4 bv0 = *(const float4*)(Cb + rb);
        float4 bv1 = *(const float4*)(Cb + rb + 4);
        float a[8]  = {av0.x, av0.y, av0.z, av0.w, av1.x, av1.y, av1.z, av1.w};
        float ba[8] = {bv0.x, bv0.y, bv0.z, bv0.w, bv1.x, bv1.y, bv1.z, bv1.w};
        f16x8 sp;
#pragma unroll
        for (int c = 0; c < 8; ++c) {
            mb[c] = mb[c] + (ba[c] - mb[c]) * 0.5f;
            ma[c] = ma[c] + (a[c] - ma[c]) * 0.5f;
            ms[c] = ms[c] + (ma[c] + mb[c] - ms[c]) * 0.5f;
            sp[c] = (ms[c] > 1.0f) ? (_Float16)1.0f : (_Float16)0.0f;
            ms[c] = (ms[c] > 1.0f) ? 0.0f : ms[c];
        }
        *(f16x8*)(SPh + ra) = sp;
    }
}

// Fused ml-scan + output GEMM: block owns 2 rows; phase 1 computes the two
// spmean rows into LDS; phase 2 does 36 wave-level dots (18 l x 2 rows)
// against W2 with shuffle reduction. Replaces k_scan2 + k_out and the
// spmean global round-trip.
__global__ __launch_bounds__(256) void k_tail(
    const float* __restrict__ H, const float* __restrict__ b1,
    const float* __restrict__ W2, const float* __restrict__ b2,
    float* __restrict__ out)
{
    __shared__ float sm[2][512];
    const int tid  = threadIdx.x;
    const int half = tid >> 7;                 // which of the 2 rows
    const int r    = blockIdx.x * 2 + half;    // global row 0..2047
    const int f    = (tid & 127) << 2;

    float4 b1v = *(const float4*)(b1 + f);
    float bb[4] = {b1v.x, b1v.y, b1v.z, b1v.w};
    float ml[4] = {0, 0, 0, 0}, acc[4] = {0, 0, 0, 0};
#pragma unroll
    for (int t = 0; t < 8; ++t) {
        float4 hv = *(const float4*)(H + ((size_t)(t * 2048 + r) << 9) + f);
        float h[4] = {hv.x, hv.y, hv.z, hv.w};
#pragma unroll
        for (int c = 0; c < 4; ++c) {
            float hb = h[c] + bb[c];
            ml[c] = ml[c] + (hb - ml[c]) * 0.5f;
            float s2 = (ml[c] > 0.5f) ? 1.0f : 0.0f;
            acc[c] += s2;
            ml[c] = (ml[c] > 0.5f) ? 0.0f : ml[c];
        }
    }
    *(float4*)&sm[half][f] =
        make_float4(acc[0] * 0.125f, acc[1] * 0.125f, acc[2] * 0.125f, acc[3] * 0.125f);
    __syncthreads();

    const int wave = tid >> 6;
    const int lane = tid & 63;
#pragma unroll
    for (int d = wave; d < 36; d += 4) {
        const int row = (d >= 18) ? 1 : 0;
        const int l   = d - row * 18;
        const float4 w0 = *(const float4*)(W2 + (size_t)l * 512 + lane * 8);
        const float4 w1 = *(const float4*)(W2 + (size_t)l * 512 + lane * 8 + 4);
        const float4 s0 = *(const float4*)&sm[row][lane * 8];
        const float4 s1 = *(const float4*)&sm[row][lane * 8 + 4];
        float p = s0.x * w0.x + s0.y * w0.y + s0.z * w0.z + s0.w * w0.w
                + s1.x * w1.x + s1.y * w1.y + s1.z * w1.z + s1.w * w1.w;
#pragma unroll
        for (int off = 32; off; off >>= 1) p += __shfl_xor(p, off);
        if (lane == 0) {
            const int rr = blockIdx.x * 2 + row;
            const int b = rr >> 5, s = rr & 31;
            out[((size_t)(b * 18 + l) << 5) + s] = p + b2[l];
        }
    }
}

extern "C" void kernel_launch(void* const* d_in, const int* in_sizes, int n_in,
                              void* d_out, int out_size, void* d_ws, size_t ws_size,
                              hipStream_t stream)
{
    const float* SE = (const float*)d_in[0];   // [8,64,3136]
    const float* TE = (const float*)d_in[1];   // [8,2048,3136]
    const float* Wb = (const float*)d_in[2];   // [512,3136]
    const float* Wa = (const float*)d_in[3];   // [512,3136]
    const float* W1 = (const float*)d_in[4];   // [512,512]
    const float* b1 = (const float*)d_in[5];   // [512]
    const float* W2 = (const float*)d_in[6];   // [18,512]
    const float* b2 = (const float*)d_in[7];   // [18]
    float* out = (float*)d_out;                // [64,18,32]

    char* ws = (char*)d_ws;
    size_t off = 0;
    float*    Abuf   = (float*)(ws + off);     off += 33554432;  // [16384,512] f32 (apical, then H)
    float*    Cb     = (float*)(ws + off);     off += 1048576;   // [512,512] f32
    float*    spare  = (float*)(ws + off);     off += 4194304;   // (unused, kept for layout stability)
    _Float16* SPh    = (_Float16*)(ws + off);  off += 16777216;  // [16384,512] f16
    _Float16* W1h    = (_Float16*)(ws + off);  off += 524288;
    _Float16* W1l    = (_Float16*)(ws + off);  off += 524288;
    _Float16* Wah    = (_Float16*)(ws + off);  off += 3211264;
    _Float16* Wal    = (_Float16*)(ws + off);  off += 3211264;
    _Float16* Wbh    = (_Float16*)(ws + off);  off += 3211264;
    _Float16* Wbl    = (_Float16*)(ws + off);  off += 3211264;
    (void)spare;

    // Basal partial buffers alias SPh: PCb[16][512*512] f32 = 16 MB.
    // Lifetime: written by k_front, read by k_comb, dead before k_scan1
    // overwrites the region with SPh.
    float* PCb = (float*)SPh;

    hipLaunchKernelGGL(k_cvt_all, dim3(1696), dim3(256), 0, stream,
                       Wa, Wb, W1, Wah, Wal, Wbh, Wbl, W1h, W1l);
    hipLaunchKernelGGL(k_front, dim3(512), dim3(256), 0, stream,
                       TE, SE, Wah, Wal, Wbh, Wbl, Abuf, PCb);
    hipLaunchKernelGGL(k_comb, dim3(256), dim3(256), 0, stream, PCb, Cb);
    hipLaunchKernelGGL(k_scan1, dim3(512), dim3(256), 0, stream, Abuf, Cb, SPh);
    hipLaunchKernelGGL(k_gemm3, dim3(512), dim3(256), 0, stream, SPh, W1h, W1l, Abuf);
    hipLaunchKernelGGL(k_tail, dim3(1024), dim3(256), 0, stream, Abuf, b1, W2, b2, out);
}